// Round 4
// baseline (9221.211 us; speedup 1.0000x reference)
//
#include <hip/hip_runtime.h>
#include <stdint.h>

#define H_ 1024
#define NG_ 4096   // 4*H

typedef float f32x4 __attribute__((ext_vector_type(4)));
typedef __bf16 bf16x8 __attribute__((ext_vector_type(8)));

__device__ __forceinline__ unsigned short f2bf(float f) {
  union { float f; uint32_t u; } v; v.f = f;
  uint32_t r = v.u + 0x7FFFu + ((v.u >> 16) & 1u);
  return (unsigned short)(r >> 16);
}
__device__ __forceinline__ float bf2f(unsigned short b) {
  union { uint32_t u; float f; } v; v.u = ((uint32_t)b) << 16; return v.f;
}

__device__ __forceinline__ void gload_lds16(const void* g, void* l) {
  __builtin_amdgcn_global_load_lds(
      (const __attribute__((address_space(1))) void*)g,
      (__attribute__((address_space(3))) void*)l, 16, 0, 0);
}

__device__ __forceinline__ float sigm(float x) { return 1.f / (1.f + __expf(-x)); }
__device__ __forceinline__ float tanh_(float x) { return 1.f - 2.f / (__expf(2.f * x) + 1.f); }

// ---------------------------------------------------------------------------
// Weight prep: permute rows r = (j>>4)*64 + gate*16 + (j&15)  (old = gate*H + j)
// so a 64-wide column group holds 16 units x 4 gates, gate index = n-frag index.
// ---------------------------------------------------------------------------
__global__ void prep_w0(const float* __restrict__ Whh0, unsigned short* __restrict__ Wr) {
  int i = (blockIdx.x * 256 + threadIdx.x) * 4;           // over 4096*1024
  int r = i >> 10, k = i & 1023;
  int gate = (r >> 4) & 3;
  int j = ((r >> 6) << 4) + (r & 15);
  const float4 v = *(const float4*)(Whh0 + (size_t)(gate * H_ + j) * H_ + k);
  ushort4 o; o.x = f2bf(v.x); o.y = f2bf(v.y); o.z = f2bf(v.z); o.w = f2bf(v.w);
  *(ushort4*)(Wr + i) = o;
}

__global__ void prep_wcat(const float* __restrict__ Wih1, const float* __restrict__ Whh1,
                          unsigned short* __restrict__ Wr) {
  int i = (blockIdx.x * 256 + threadIdx.x) * 4;           // over 4096*2048
  int r = i >> 11, k = i & 2047;
  int gate = (r >> 4) & 3;
  int j = ((r >> 6) << 4) + (r & 15);
  const float* src = (k < 1024) ? (Wih1 + (size_t)(gate * H_ + j) * H_ + k)
                                : (Whh1 + (size_t)(gate * H_ + j) * H_ + (k - 1024));
  const float4 v = *(const float4*)src;
  ushort4 o; o.x = f2bf(v.x); o.y = f2bf(v.y); o.z = f2bf(v.z); o.w = f2bf(v.w);
  *(ushort4*)(Wr + (size_t)r * 2048 + k) = o;
}

__global__ void prep_small(const float* __restrict__ Wih0,
                           const float* __restrict__ bih0, const float* __restrict__ bhh0,
                           const float* __restrict__ bih1, const float* __restrict__ bhh1,
                           float* __restrict__ bias0r, float* __restrict__ bias1r,
                           float* __restrict__ wi0r) {
  int r = blockIdx.x * 256 + threadIdx.x;                 // over 4096
  int gate = (r >> 4) & 3;
  int j = ((r >> 6) << 4) + (r & 15);
  int old = gate * H_ + j;
  bias0r[r] = bih0[old] + bhh0[old];
  bias1r[r] = bih1[old] + bhh1[old];
  wi0r[r * 2 + 0] = Wih0[old * 2 + 0];
  wi0r[r * 2 + 1] = Wih0[old * 2 + 1];
}

__global__ void prep_state(const float* __restrict__ h, const float* __restrict__ c,
                           unsigned short* __restrict__ h0b, unsigned short* __restrict__ h1b,
                           float* __restrict__ c0, float* __restrict__ c1, int bh) {
  int i = (blockIdx.x * 256 + threadIdx.x) * 4;           // over B*H
  float4 a = *(const float4*)(h + i);
  float4 b = *(const float4*)(h + (size_t)bh + i);
  ushort4 oa; oa.x = f2bf(a.x); oa.y = f2bf(a.y); oa.z = f2bf(a.z); oa.w = f2bf(a.w);
  ushort4 ob; ob.x = f2bf(b.x); ob.y = f2bf(b.y); ob.z = f2bf(b.z); ob.w = f2bf(b.w);
  *(ushort4*)(h0b + i) = oa;
  *(ushort4*)(h1b + i) = ob;
  *(float4*)(c0 + i) = *(const float4*)(c + i);
  *(float4*)(c1 + i) = *(const float4*)(c + (size_t)bh + i);
}

// ---------------------------------------------------------------------------
// Fused GEMM + LSTM cell, 256x256 tile, BK=64, 8 waves (2M x 4N), 512 thr.
// Depth-1 register-pipelined 4-phase schedule: phase (ks,mh) issues the NEXT
// phase's ds_reads, MFMAs on regs read one phase earlier; compiler emits the
// counted lgkmcnt. Counted vmcnt(4) once per K-tile. XOR-swizzled LDS.
// Phases: P0(ks0,mlo) P1(ks0,mhi) P2(ks1,mlo) P3(ks1,mhi).
// Stage slots: P0:A(u+1,h0) P1:A(u+1,h1) P3:B(u+2,h0)+B(u+2,h1).
// ---------------------------------------------------------------------------
__global__ void __launch_bounds__(512, 2)
lstm_gemm_cell(const unsigned short* __restrict__ A0,
               const unsigned short* __restrict__ A1,
               int Ktot,
               const unsigned short* __restrict__ Bw,
               const float* __restrict__ biasr,
               const float* __restrict__ wi0r,
               const int* __restrict__ xidx,
               int have_x,
               float* __restrict__ Cst,
               unsigned short* __restrict__ Hout) {
  __shared__ unsigned short As[2][256 * 64];
  __shared__ unsigned short Bs[2][256 * 64];

  const int tid  = threadIdx.x;
  const int lane = tid & 63;
  const int wv   = tid >> 6;          // 0..7
  const int wm   = wv >> 2;           // 0..1  (M half)
  const int wn   = wv & 3;            // 0..3  (N quarter)
  const int tile_m = blockIdx.y * 256;
  const int tile_n = blockIdx.x * 256;

  // staging geometry: one gload round = 512 thr x 16B = 64 rows
  const int rowt = tid >> 3;                          // 0..63
  const int cb8  = (tid & 7) * 8;                     // LDS col, linear dest
  const int ce   = (((tid & 7) ^ (rowt & 7)) * 8);    // global col: inv-swizzled src

  const int NK = Ktot >> 6;

  auto stageA = [&](int v, int half) {               // 2 gloads (16 KB piece)
    const int d = v & 1;
    const int kb = v << 6;
    const unsigned short* Ap = A0; int kl = kb;
    if (kb >= 1024) { Ap = A1; kl = kb - 1024; }
#pragma unroll
    for (int i = 0; i < 2; ++i) {
      const int row = half * 128 + i * 64 + rowt;
      gload_lds16(Ap + (size_t)(tile_m + row) * H_ + kl + ce, (void*)&As[d][row * 64 + cb8]);
    }
  };
  auto stageB = [&](int v, int half) {
    const int d = v & 1;
    const int kb = v << 6;
#pragma unroll
    for (int i = 0; i < 2; ++i) {
      const int row = half * 128 + i * 64 + rowt;
      gload_lds16(Bw + (size_t)(tile_n + row) * (size_t)Ktot + kb + ce, (void*)&Bs[d][row * 64 + cb8]);
    }
  };

  f32x4 acc[8][4];
#pragma unroll
  for (int m = 0; m < 8; ++m)
#pragma unroll
    for (int n = 0; n < 4; ++n) acc[m][n] = (f32x4)0.f;

  // fragment read geometry (swizzled): row r holds logical byte-chunk c at (c^(r&7))*16
  const int cl  = lane & 15;
  const int khi = lane >> 4;          // 0..3
  const int ksw0 = ((0 + khi) ^ (cl & 7)) * 16;
  const int ksw1 = ((4 + khi) ^ (cl & 7)) * 16;

  const char* Ab0 = (const char*)&As[0][0] + (wm * 128 + cl) * 128;
  const char* Bb0 = (const char*)&Bs[0][0] + (wn * 64 + cl) * 128;

  bf16x8 aX[4], aY[4], bX[4], bY[4];

#define MFMA16(AF, BF, MOFF)                                                         \
  _Pragma("unroll")                                                                  \
  for (int n_ = 0; n_ < 4; ++n_)                                                     \
  _Pragma("unroll")                                                                  \
  for (int i_ = 0; i_ < 4; ++i_)                                                     \
    acc[(MOFF) + i_][n_] =                                                           \
        __builtin_amdgcn_mfma_f32_16x16x32_bf16(AF[i_], BF[n_], acc[(MOFF) + i_][n_], 0, 0, 0);

  // ---- prologue: tile0 (A+B) + B(tile1); keep B(1) in flight (vmcnt 4) ----
  stageA(0, 0); stageA(0, 1);
  stageB(0, 0); stageB(0, 1);
  stageB(1, 0); stageB(1, 1);
  asm volatile("s_waitcnt vmcnt(4)" ::: "memory");
  __builtin_amdgcn_sched_barrier(0);
  __builtin_amdgcn_s_barrier();
  // initial fragment reads: tile0, ks0, mlo + B ks0
#pragma unroll
  for (int i = 0; i < 4; ++i) aX[i] = *(const bf16x8*)(Ab0 + i * 2048 + ksw0);
#pragma unroll
  for (int n = 0; n < 4; ++n) bX[n] = *(const bf16x8*)(Bb0 + n * 2048 + ksw0);

  for (int u = 0; u < NK; ++u) {
    const char* Ab = Ab0 + (u & 1) * 32768;
    const char* Bb = Bb0 + (u & 1) * 32768;
    const int un = (u + 1 < NK) ? u + 1 : NK - 2;                     // A stage target
    const int ub = (u + 2 < NK) ? u + 2 : (((u + 2) & 1) ? NK - 1 : NK - 2); // B stage
    const int ur = (u + 1 < NK) ? u + 1 : u;                          // next-tile reads
    const char* Abn = Ab0 + (ur & 1) * 32768;
    const char* Bbn = Bb0 + (ur & 1) * 32768;

    // ---- P0 (ks0, mlo): compute aX*bX ; issue aY <- A[t, mhi, ks0] ----
#pragma unroll
    for (int i = 0; i < 4; ++i) aY[i] = *(const bf16x8*)(Ab + 8192 + i * 2048 + ksw0);
    stageA(un, 0);
    __builtin_amdgcn_s_barrier();
    __builtin_amdgcn_s_setprio(1);
    MFMA16(aX, bX, 0);
    __builtin_amdgcn_s_setprio(0);
    __builtin_amdgcn_s_barrier();

    // ---- P1 (ks0, mhi): compute aY*bX ; issue aX <- A[t, mlo, ks1], bY <- B[t, ks1] ----
#pragma unroll
    for (int i = 0; i < 4; ++i) aX[i] = *(const bf16x8*)(Ab + i * 2048 + ksw1);
#pragma unroll
    for (int n = 0; n < 4; ++n) bY[n] = *(const bf16x8*)(Bb + n * 2048 + ksw1);
    stageA(un, 1);
    __builtin_amdgcn_s_barrier();
    __builtin_amdgcn_s_setprio(1);
    MFMA16(aY, bX, 4);
    __builtin_amdgcn_s_setprio(0);
    __builtin_amdgcn_s_barrier();

    // ---- P2 (ks1, mlo): compute aX*bY ; issue aY <- A[t, mhi, ks1] ----
#pragma unroll
    for (int i = 0; i < 4; ++i) aY[i] = *(const bf16x8*)(Ab + 8192 + i * 2048 + ksw1);
    __builtin_amdgcn_s_barrier();
    __builtin_amdgcn_s_setprio(1);
    MFMA16(aX, bY, 0);
    __builtin_amdgcn_s_setprio(0);
    __builtin_amdgcn_s_barrier();

    // ---- P3 (ks1, mhi): compute aY*bY ; post-barrier issue next-tile aX,bX ----
    stageB(ub, 0); stageB(ub, 1);
    asm volatile("s_waitcnt vmcnt(4)" ::: "memory");   // tile u+1 fully resident
    __builtin_amdgcn_sched_barrier(0);
    __builtin_amdgcn_s_barrier();
#pragma unroll
    for (int i = 0; i < 4; ++i) aX[i] = *(const bf16x8*)(Abn + i * 2048 + ksw0);
#pragma unroll
    for (int n = 0; n < 4; ++n) bX[n] = *(const bf16x8*)(Bbn + n * 2048 + ksw0);
    __builtin_amdgcn_s_setprio(1);
    MFMA16(aY, bY, 4);
    __builtin_amdgcn_s_setprio(0);
    __builtin_amdgcn_s_barrier();
  }
#undef MFMA16

  asm volatile("s_waitcnt vmcnt(0) lgkmcnt(0)" ::: "memory");  // drain tail

  // ---- epilogue: fused LSTM cell (gate = n-frag index) ----
  const int jgrp = (tile_n >> 6) + wn;
  const int j = jgrp * 16 + cl;
  float bias[4], w0v[4] = {0, 0, 0, 0}, w1v[4] = {0, 0, 0, 0};
#pragma unroll
  for (int n = 0; n < 4; ++n) {
    int colr = tile_n + wn * 64 + n * 16 + cl;
    bias[n] = biasr[colr];
    if (have_x) { w0v[n] = wi0r[colr * 2]; w1v[n] = wi0r[colr * 2 + 1]; }
  }
#pragma unroll
  for (int m = 0; m < 8; ++m) {
#pragma unroll
    for (int q = 0; q < 4; ++q) {
      int row = tile_m + wm * 128 + m * 16 + khi * 4 + q;
      float gi = acc[m][0][q] + bias[0];
      float gf = acc[m][1][q] + bias[1];
      float gg = acc[m][2][q] + bias[2];
      float go = acc[m][3][q] + bias[3];
      if (have_x) {
        int x = xidx[row];
        gi += x ? w1v[0] : w0v[0];
        gf += x ? w1v[1] : w0v[1];
        gg += x ? w1v[2] : w0v[2];
        go += x ? w1v[3] : w0v[3];
      }
      size_t off = (size_t)row * H_ + j;
      float cp = Cst[off];
      float cn = sigm(gf) * cp + sigm(gi) * tanh_(gg);
      float hn = sigm(go) * tanh_(cn);
      Cst[off] = cn;
      Hout[off] = f2bf(hn);
    }
  }
}

// ---------------------------------------------------------------------------
// fc head: logits = h1 @ fcW^T + fcb, write out[b,t,:], argmax -> xidx
// ---------------------------------------------------------------------------
__global__ void fc_argmax(const unsigned short* __restrict__ h1,
                          const float* __restrict__ fcW, const float* __restrict__ fcb,
                          float* __restrict__ out, int* __restrict__ xidx,
                          int t, int pred_len) {
  const int lane = threadIdx.x & 63;
  const int wv = threadIdx.x >> 6;
  const int row = blockIdx.x * 4 + wv;
  const unsigned short* hp = h1 + (size_t)row * H_ + lane * 16;
  float d0 = 0.f, d1 = 0.f;
#pragma unroll
  for (int u = 0; u < 2; ++u) {
    ushort4 ha = *(const ushort4*)(hp + u * 8);
    ushort4 hb = *(const ushort4*)(hp + u * 8 + 4);
    float hv[8] = { bf2f(ha.x), bf2f(ha.y), bf2f(ha.z), bf2f(ha.w),
                    bf2f(hb.x), bf2f(hb.y), bf2f(hb.z), bf2f(hb.w) };
#pragma unroll
    for (int e = 0; e < 8; ++e) {
      int k = lane * 16 + u * 8 + e;
      d0 += hv[e] * fcW[k];
      d1 += hv[e] * fcW[H_ + k];
    }
  }
#pragma unroll
  for (int off = 32; off > 0; off >>= 1) {
    d0 += __shfl_xor(d0, off);
    d1 += __shfl_xor(d1, off);
  }
  if (lane == 0) {
    d0 += fcb[0]; d1 += fcb[1];
    size_t o = ((size_t)row * pred_len + t) * 2;
    out[o] = d0; out[o + 1] = d1;
    xidx[row] = (d1 > d0) ? 1 : 0;
  }
}

// ---------------------------------------------------------------------------
extern "C" void kernel_launch(void* const* d_in, const int* in_sizes, int n_in,
                              void* d_out, int out_size, void* d_ws, size_t ws_size,
                              hipStream_t stream) {
  const float* h     = (const float*)d_in[0];
  const float* c     = (const float*)d_in[1];
  const float* Wih0  = (const float*)d_in[2];
  const float* Whh0  = (const float*)d_in[3];
  const float* bih0  = (const float*)d_in[4];
  const float* bhh0  = (const float*)d_in[5];
  const float* Wih1  = (const float*)d_in[6];
  const float* Whh1  = (const float*)d_in[7];
  const float* bih1  = (const float*)d_in[8];
  const float* bhh1  = (const float*)d_in[9];
  const float* fcW   = (const float*)d_in[10];
  const float* fcb   = (const float*)d_in[11];

  const int B = in_sizes[0] / (2 * H_);           // 4096
  const int pred_len = out_size / (B * 2);        // 64
  const int BH = B * H_;                          // 4194304

  size_t off = 0;
  auto carve = [&](size_t bytes) -> void* {
    void* p = (char*)d_ws + off;
    off += (bytes + 255) & ~(size_t)255;
    return p;
  };
  unsigned short* Whh0r = (unsigned short*)carve((size_t)NG_ * 1024 * 2);
  unsigned short* Wcatr = (unsigned short*)carve((size_t)NG_ * 2048 * 2);
  unsigned short* h0b[2], *h1b[2];
  h0b[0] = (unsigned short*)carve((size_t)BH * 2);
  h0b[1] = (unsigned short*)carve((size_t)BH * 2);
  h1b[0] = (unsigned short*)carve((size_t)BH * 2);
  h1b[1] = (unsigned short*)carve((size_t)BH * 2);
  float* c0 = (float*)carve((size_t)BH * 4);
  float* c1 = (float*)carve((size_t)BH * 4);
  float* bias0r = (float*)carve(NG_ * 4);
  float* bias1r = (float*)carve(NG_ * 4);
  float* wi0r   = (float*)carve(NG_ * 2 * 4);
  int*   xidx   = (int*)carve(B * 4);

  hipLaunchKernelGGL(prep_w0,   dim3((NG_ * 1024 / 4) / 256), dim3(256), 0, stream, Whh0, Whh0r);
  hipLaunchKernelGGL(prep_wcat, dim3((NG_ * 2048 / 4) / 256), dim3(256), 0, stream, Wih1, Whh1, Wcatr);
  hipLaunchKernelGGL(prep_small, dim3(NG_ / 256), dim3(256), 0, stream,
                     Wih0, bih0, bhh0, bih1, bhh1, bias0r, bias1r, wi0r);
  hipLaunchKernelGGL(prep_state, dim3((BH / 4) / 256), dim3(256), 0, stream,
                     h, c, h0b[0], h1b[0], c0, c1, BH);

  dim3 ggrid(NG_ / 256, B / 256);                 // 16 x 16 = 256 blocks (1/CU)
  dim3 gblk(512);
  float* out = (float*)d_out;

  for (int t = 0; t < pred_len; ++t) {
    const int cur = t & 1, nxt = cur ^ 1;
    hipLaunchKernelGGL(lstm_gemm_cell, ggrid, gblk, 0, stream,
                       h0b[cur], (const unsigned short*)nullptr, 1024, Whh0r,
                       bias0r, wi0r, xidx, (t > 0) ? 1 : 0, c0, h0b[nxt]);
    hipLaunchKernelGGL(lstm_gemm_cell, ggrid, gblk, 0, stream,
                       h0b[nxt], h1b[cur], 2048, Wcatr,
                       bias1r, (const float*)nullptr, (const int*)nullptr, 0, c1, h1b[nxt]);
    hipLaunchKernelGGL(fc_argmax, dim3(B / 4), dim3(256), 0, stream,
                       h1b[nxt], fcW, fcb, out, xidx, t, pred_len);
  }
}